// Round 9
// baseline (234.705 us; speedup 1.0000x reference)
//
#include <hip/hip_runtime.h>
#include <hip/hip_cooperative_groups.h>
#include <cstddef>

namespace cg = cooperative_groups;

// LinOSS-IM: P=256, H=128, B=4, L=4096
#define P_DIM 256
#define H_DIM 128
#define B_SZ 4
#define L_SEQ 4096
#define PC 512                      // 2*P real components (re,im interleaved)
#define CL 32                       // scan chunk length
#define CLOG 5                      // log2(CL)
#define NC (L_SEQ / CL)             // 128 chunks
#define OUT_BASE (B_SZ * L_SEQ * H_DIM)

typedef __attribute__((ext_vector_type(8))) short s8v;   // 8 bf16 (4 VGPRs)
typedef __attribute__((ext_vector_type(4))) float f32x4; // MFMA accumulator

// ---- bf16 helpers (manual RNE) --------------------------------------------
__device__ __forceinline__ unsigned short f2bf(float x) {
  unsigned u = __builtin_bit_cast(unsigned, x);
  unsigned r = (u + 0x7FFFu + ((u >> 16) & 1u)) >> 16;
  return (unsigned short)r;
}
__device__ __forceinline__ float bf2f(unsigned short h) {
  return __builtin_bit_cast(float, (unsigned)h << 16);
}
__device__ __forceinline__ void f2hl(float x, short& h, short& l) {
  unsigned short hb = f2bf(x);
  float hf = bf2f(hb);
  unsigned short lb = f2bf(x - hf);
  h = (short)hb; l = (short)lb;
}

// M is REAL => complex recurrence splits into independent re/im chains.
__device__ __forceinline__ void make_M(const float* A_diag, const float* step, int p,
                                       float& M11, float& M12, float& M21, float& M22) {
  float Ad = A_diag[p], s = step[p];
  float sig = 1.0f / fmaf(s * s, Ad, 1.0f);   // schur
  M11 = 1.0f - s * s * Ad * sig;
  M12 = -s * Ad * sig;
  M21 = s * sig;
  M22 = sig;
}

// ---------------------------------------------------------------------------
// K0: prep.
//  Bw f32 [n=(p,c)][h] = step[p]*B[p][h][c]                (fallback staging)
//  CtH/CtL: B-frags of Ct[k=(p,c)][h], idx=((nt*16+ks)*64+lane)*8+j,
//           n=nt*16+(lane&15), k=ks*32+(lane>>4)*8+j   (K=512 -> 16 ks)
//  BwH/BwL: B-frags of Bw[n=comp][k=h], idx=((nt*4+ks)*64+lane)*8+j (K=128)
// ---------------------------------------------------------------------------
__global__ __launch_bounds__(256) void prep_kernel(const float* __restrict__ Bin,
                                                   const float* __restrict__ Cin,
                                                   const float* __restrict__ step,
                                                   float* __restrict__ Bw,
                                                   short* __restrict__ CtH,
                                                   short* __restrict__ CtL,
                                                   short* __restrict__ BwH,
                                                   short* __restrict__ BwL) {
  int idx = blockIdx.x * 256 + threadIdx.x;    // 0..65535
  {
    int kk = idx >> 7, h = idx & 127;
    int p = kk >> 1, c = kk & 1;
    Bw[idx] = step[p] * Bin[(p * H_DIM + h) * 2 + c];
  }
  {
    int j = idx & 7, lane = (idx >> 3) & 63, ks = (idx >> 9) & 15, nt = idx >> 13;
    int h = nt * 16 + (lane & 15);
    int k = ks * 32 + (lane >> 4) * 8 + j;
    float v = Cin[(size_t)h * PC + k] * ((k & 1) ? -1.0f : 1.0f);
    short hh, ll; f2hl(v, hh, ll);
    CtH[idx] = hh; CtL[idx] = ll;
  }
  {
    int j = idx & 7, lane = (idx >> 3) & 63, ks = (idx >> 9) & 3, nt = idx >> 11;
    int n = nt * 16 + (lane & 15);              // comp
    int k = ks * 32 + (lane >> 4) * 8 + j;      // h
    int p = n >> 1, c = n & 1;
    float v = step[p] * Bin[(p * H_DIM + k) * 2 + c];
    short hh, ll; f2hl(v, hh, ll);
    BwH[idx] = hh; BwL[idx] = ll;
  }
}

// ---------------------------------------------------------------------------
// MEGA (cooperative): one block per (chunk ch, batch b). 512 thr, 64KB LDS.
// A: Bu tile [32 t][512 comp] via split-bf16 MFMA (Bw frags L2-hot) -> LDS
//    (XOR-swizzled col ^= (row&7)<<3), local 32-step scan -> carries.
// B: grid.sync; blocks ch==0 combine carries serially (M^32), write carryIn
//    + z_f/y_f tail.  C: grid.sync; seeded re-scan from LDS, pack ys bf16
//    hi|lo u32 IN PLACE (same thread+addr), out GEMM vs Ct frags.
// ---------------------------------------------------------------------------
__global__ __launch_bounds__(512, 4) void mega_kernel(const float* __restrict__ A_diag,
                                                      const float* __restrict__ step,
                                                      const float* __restrict__ U,
                                                      const short* __restrict__ BwH,
                                                      const short* __restrict__ BwL,
                                                      const short* __restrict__ CtH,
                                                      const short* __restrict__ CtL,
                                                      float* __restrict__ carries,
                                                      float* __restrict__ carryIn,
                                                      float* __restrict__ outp,
                                                      int mode) {
  __shared__ float Fs[32][512];                // 64KB exactly
  const int t = threadIdx.x;
  const int ch = blockIdx.x;                   // 0..NC-1
  const int b  = blockIdx.y;                   // 0..B_SZ-1
  const int lane = t & 63, w = t >> 6;
  const int lr = lane & 15, kb8 = (lane >> 4) * 8, rb = (lane >> 4) * 4;

  // ---- A0: stage U tile [32][128] as split-bf16 (aliased into Fs) ----
  short* Ush = (short*)&Fs[0][0];              // [32][136]
  short* Usl = Ush + 32 * 136;                 // total 17408B
  {
    const int row = t >> 4, c8 = (t & 15) * 8;
    const float* up = &U[((size_t)b * L_SEQ + (size_t)ch * CL + row) * H_DIM + c8];
    float4 u0 = *(const float4*)up, u1 = *(const float4*)(up + 4);
    s8v h8, l8; short hh, ll;
    f2hl(u0.x, hh, ll); h8[0] = hh; l8[0] = ll;
    f2hl(u0.y, hh, ll); h8[1] = hh; l8[1] = ll;
    f2hl(u0.z, hh, ll); h8[2] = hh; l8[2] = ll;
    f2hl(u0.w, hh, ll); h8[3] = hh; l8[3] = ll;
    f2hl(u1.x, hh, ll); h8[4] = hh; l8[4] = ll;
    f2hl(u1.y, hh, ll); h8[5] = hh; l8[5] = ll;
    f2hl(u1.z, hh, ll); h8[6] = hh; l8[6] = ll;
    f2hl(u1.w, hh, ll); h8[7] = hh; l8[7] = ll;
    *(s8v*)&Ush[row * 136 + c8] = h8;
    *(s8v*)&Usl[row * 136 + c8] = l8;
  }
  __syncthreads();

  // ---- A1: Bu GEMM. wave w: mt=w&1, n-tiles ntbA..ntbA+7 ----
  const int mt = w & 1;
  const int ntbA = (w >> 1) * 8;
  f32x4 accA[8] = {};
#pragma unroll
  for (int ks = 0; ks < 4; ++ks) {
    s8v ah = *(const s8v*)&Ush[(mt * 16 + lr) * 136 + ks * 32 + kb8];
    s8v al = *(const s8v*)&Usl[(mt * 16 + lr) * 136 + ks * 32 + kb8];
#pragma unroll
    for (int q = 0; q < 8; ++q) {
      size_t fo = (((size_t)(ntbA + q) * 4 + ks) * 64 + lane) * 8;
      s8v bh = *(const s8v*)&BwH[fo];
      s8v bl = *(const s8v*)&BwL[fo];
      accA[q] = __builtin_amdgcn_mfma_f32_16x16x32_bf16(ah, bh, accA[q], 0, 0, 0);
      accA[q] = __builtin_amdgcn_mfma_f32_16x16x32_bf16(al, bh, accA[q], 0, 0, 0);
      accA[q] = __builtin_amdgcn_mfma_f32_16x16x32_bf16(ah, bl, accA[q], 0, 0, 0);
    }
  }
  __syncthreads();                             // Ustage reads done

  // ---- A2: scatter acc -> Fs[time][comp], swizzled ----
#pragma unroll
  for (int q = 0; q < 8; ++q)
#pragma unroll
    for (int r = 0; r < 4; ++r) {
      int row = mt * 16 + rb + r;
      int col = (ntbA + q) * 16 + lr;
      Fs[row][col ^ ((row & 7) << 3)] = accA[q][r];
    }
  __syncthreads();

  // ---- A3: local scan (zero-init) -> carries ----
  float M11, M12, M21, M22;
  make_M(A_diag, step, t >> 1, M11, M12, M21, M22);    // t = comp
  {
    float z = 0.f, y = 0.f;
#pragma unroll 8
    for (int i = 0; i < CL; ++i) {
      float f = Fs[i][t ^ ((i & 7) << 3)];
      float zf = z + f;
      z = fmaf(M11, zf, M12 * y);
      y = fmaf(M21, zf, M22 * y);
    }
    size_t o = (((size_t)b * NC + ch) * PC + t) * 2;
    carries[o] = z; carries[o + 1] = y;
  }
  cg::this_grid().sync();

  // ---- B: combine (blocks ch==0 only), M^CL via CLOG squarings ----
  if (ch == 0) {
    float X11 = M11, X12 = M12, X21 = M21, X22 = M22;
#pragma unroll
    for (int i = 0; i < CLOG; ++i) {
      float a = X11 * X11 + X12 * X21;
      float bb = X11 * X12 + X12 * X22;
      float cc = X21 * X11 + X22 * X21;
      float dd = X21 * X12 + X22 * X22;
      X11 = a; X12 = bb; X21 = cc; X22 = dd;
    }
    float z = 0.f, y = 0.f;
#pragma unroll 8
    for (int k = 0; k < NC; ++k) {
      size_t o = (((size_t)b * NC + k) * PC + t) * 2;
      carryIn[o] = z; carryIn[o + 1] = y;
      float sz = carries[o], sy = carries[o + 1];
      float zn = X11 * z + X12 * y + sz;
      float yn = X21 * z + X22 * y + sy;
      z = zn; y = yn;
    }
    const int c = t & 1, p = t >> 1;
    if (mode == 1) {
      if (c == 0) {
        outp[OUT_BASE + (size_t)b * 256 + p] = z;
        outp[OUT_BASE + 1024 + (size_t)b * 256 + p] = y;
      }
    } else if (mode == 2) {
      outp[OUT_BASE + (size_t)c * 1024 + (size_t)b * 256 + p] = z;
      outp[OUT_BASE + 2048 + (size_t)c * 1024 + (size_t)b * 256 + p] = y;
    } else {
      outp[OUT_BASE + (size_t)b * PC + t] = z;
      outp[OUT_BASE + 2048 + (size_t)b * PC + t] = y;
    }
  }
  cg::this_grid().sync();

  // ---- C: seeded re-scan, pack ys bf16 hi|lo u32 in place ----
  {
    size_t o = (((size_t)b * NC + ch) * PC + t) * 2;
    float z = carryIn[o], y = carryIn[o + 1];
#pragma unroll 8
    for (int i = 0; i < CL; ++i) {
      const int cswz = t ^ ((i & 7) << 3);
      float f = Fs[i][cswz];
      float zf = z + f;
      z = fmaf(M11, zf, M12 * y);
      y = fmaf(M21, zf, M22 * y);
      short hh, ll; f2hl(y, hh, ll);
      unsigned u = ((unsigned)(unsigned short)hh << 16) | (unsigned)(unsigned short)ll;
      Fs[i][cswz] = __builtin_bit_cast(float, u);   // same thread+addr: race-free
    }
  }
  __syncthreads();

  // ---- C2: out GEMM [32 t][128 h] = ys[32][512] x Ct[512][128] ----
  const int ntbC = (w >> 1) * 2;
  const int mrow = mt * 16 + lr;
  const int msw = (mrow & 7) << 3;
  f32x4 accC[2] = {};
  for (int ks = 0; ks < 16; ++ks) {
    const unsigned* ap = (const unsigned*)&Fs[mrow][(ks * 32 + kb8) ^ msw];
    uint4 w0 = *(const uint4*)ap;
    uint4 w1 = *(const uint4*)(ap + 4);
    s8v ah, al;
    ah[0] = (short)(w0.x >> 16); al[0] = (short)(w0.x & 0xffff);
    ah[1] = (short)(w0.y >> 16); al[1] = (short)(w0.y & 0xffff);
    ah[2] = (short)(w0.z >> 16); al[2] = (short)(w0.z & 0xffff);
    ah[3] = (short)(w0.w >> 16); al[3] = (short)(w0.w & 0xffff);
    ah[4] = (short)(w1.x >> 16); al[4] = (short)(w1.x & 0xffff);
    ah[5] = (short)(w1.y >> 16); al[5] = (short)(w1.y & 0xffff);
    ah[6] = (short)(w1.z >> 16); al[6] = (short)(w1.z & 0xffff);
    ah[7] = (short)(w1.w >> 16); al[7] = (short)(w1.w & 0xffff);
#pragma unroll
    for (int q = 0; q < 2; ++q) {
      size_t fo = (((size_t)(ntbC + q) * 16 + ks) * 64 + lane) * 8;
      s8v bh = *(const s8v*)&CtH[fo];
      s8v bl = *(const s8v*)&CtL[fo];
      accC[q] = __builtin_amdgcn_mfma_f32_16x16x32_bf16(ah, bh, accC[q], 0, 0, 0);
      accC[q] = __builtin_amdgcn_mfma_f32_16x16x32_bf16(al, bh, accC[q], 0, 0, 0);
      accC[q] = __builtin_amdgcn_mfma_f32_16x16x32_bf16(ah, bl, accC[q], 0, 0, 0);
    }
  }
  const size_t rowbase = (size_t)b * L_SEQ + (size_t)ch * CL;
#pragma unroll
  for (int q = 0; q < 2; ++q) {
    const int col = (ntbC + q) * 16 + lr;
#pragma unroll
    for (int r = 0; r < 4; ++r)
      outp[(rowbase + mt * 16 + rb + r) * H_DIM + col] = accC[q][r];
  }
}

// ===========================================================================
// Fallback pipeline (round-7, PASSED at 126.6us): used only if cooperative
// launch returns an error (e.g. co-residency refused).
// ===========================================================================
template<int KTOT, int LDC>
__global__ __launch_bounds__(256) void gemm_nt_mfma(const float* __restrict__ A,
                                                    const float* __restrict__ Bt,
                                                    float* __restrict__ Cout) {
  __shared__ short As_h[64][72], As_l[64][72];
  __shared__ short Bs_h[128][72], Bs_l[128][72];
  const int t = threadIdx.x;
  const int lane = t & 63;
  const int wid = t >> 6;
  const int wm = (wid & 1) * 32;
  const int wn = (wid >> 1) * 64;
  const int m0 = blockIdx.y * 64;
  const int n0 = blockIdx.x * 128;
  const int lr  = lane & 15;
  const int kb8 = (lane >> 4) * 8;
  const int ar = t >> 4;
  const int ac = (t & 15) * 4;
  f32x4 acc[2][4] = {};
  for (int ks = 0; ks < KTOT / 64; ++ks) {
    const int k0 = ks * 64;
    float4 av[4], bv[8];
#pragma unroll
    for (int j = 0; j < 4; ++j)
      av[j] = *(const float4*)&A[(size_t)(m0 + ar + 16 * j) * KTOT + k0 + ac];
#pragma unroll
    for (int j = 0; j < 8; ++j)
      bv[j] = *(const float4*)&Bt[(size_t)(n0 + ar + 16 * j) * KTOT + k0 + ac];
    __syncthreads();
#pragma unroll
    for (int j = 0; j < 4; ++j) {
      short4 h4, l4;
      f2hl(av[j].x, h4.x, l4.x); f2hl(av[j].y, h4.y, l4.y);
      f2hl(av[j].z, h4.z, l4.z); f2hl(av[j].w, h4.w, l4.w);
      *(short4*)&As_h[ar + 16 * j][ac] = h4;
      *(short4*)&As_l[ar + 16 * j][ac] = l4;
    }
#pragma unroll
    for (int j = 0; j < 8; ++j) {
      short4 h4, l4;
      f2hl(bv[j].x, h4.x, l4.x); f2hl(bv[j].y, h4.y, l4.y);
      f2hl(bv[j].z, h4.z, l4.z); f2hl(bv[j].w, h4.w, l4.w);
      *(short4*)&Bs_h[ar + 16 * j][ac] = h4;
      *(short4*)&Bs_l[ar + 16 * j][ac] = l4;
    }
    __syncthreads();
#pragma unroll
    for (int kb = 0; kb < 2; ++kb) {
      s8v ah[2], al[2], bh[4], bl[4];
#pragma unroll
      for (int ti = 0; ti < 2; ++ti) {
        ah[ti] = *(const s8v*)&As_h[wm + ti * 16 + lr][kb * 32 + kb8];
        al[ti] = *(const s8v*)&As_l[wm + ti * 16 + lr][kb * 32 + kb8];
      }
#pragma unroll
      for (int tj = 0; tj < 4; ++tj) {
        bh[tj] = *(const s8v*)&Bs_h[wn + tj * 16 + lr][kb * 32 + kb8];
        bl[tj] = *(const s8v*)&Bs_l[wn + tj * 16 + lr][kb * 32 + kb8];
      }
#pragma unroll
      for (int ti = 0; ti < 2; ++ti)
#pragma unroll
        for (int tj = 0; tj < 4; ++tj) {
          acc[ti][tj] = __builtin_amdgcn_mfma_f32_16x16x32_bf16(ah[ti], bh[tj], acc[ti][tj], 0, 0, 0);
          acc[ti][tj] = __builtin_amdgcn_mfma_f32_16x16x32_bf16(ah[ti], bl[tj], acc[ti][tj], 0, 0, 0);
          acc[ti][tj] = __builtin_amdgcn_mfma_f32_16x16x32_bf16(al[ti], bh[tj], acc[ti][tj], 0, 0, 0);
        }
    }
  }
  const int rb = (lane >> 4) * 4;
#pragma unroll
  for (int ti = 0; ti < 2; ++ti)
#pragma unroll
    for (int tj = 0; tj < 4; ++tj) {
      const int row = m0 + wm + ti * 16 + rb;
      const int col = n0 + wn + tj * 16 + lr;
#pragma unroll
      for (int r = 0; r < 4; ++r)
        Cout[(size_t)(row + r) * LDC + col] = acc[ti][tj][r];
    }
}

__global__ __launch_bounds__(512) void scan_local_kernel(const float* __restrict__ A_diag,
                                                         const float* __restrict__ step,
                                                         const float* __restrict__ sBu,
                                                         float* __restrict__ carries) {
  const int t = threadIdx.x;
  const int b = blockIdx.y, ch = blockIdx.x;
  float M11, M12, M21, M22;
  make_M(A_diag, step, t >> 1, M11, M12, M21, M22);
  const float* fp = sBu + ((size_t)b * L_SEQ + (size_t)ch * CL) * PC + t;
  float z = 0.f, y = 0.f;
#pragma unroll 8
  for (int i = 0; i < CL; ++i) {
    float f = fp[(size_t)i * PC];
    float zf = z + f;
    z = fmaf(M11, zf, M12 * y);
    y = fmaf(M21, zf, M22 * y);
  }
  size_t o = (((size_t)b * NC + ch) * PC + t) * 2;
  carries[o] = z; carries[o + 1] = y;
}

__global__ __launch_bounds__(512) void combine_kernel(const float* __restrict__ A_diag,
                                                      const float* __restrict__ step,
                                                      const float* __restrict__ carries,
                                                      float* __restrict__ carryIn,
                                                      float* __restrict__ outp,
                                                      int mode) {
  const int t = threadIdx.x;
  const int b = blockIdx.x;
  float M11, M12, M21, M22;
  make_M(A_diag, step, t >> 1, M11, M12, M21, M22);
  float X11 = M11, X12 = M12, X21 = M21, X22 = M22;
#pragma unroll
  for (int i = 0; i < CLOG; ++i) {
    float a = X11 * X11 + X12 * X21;
    float bb = X11 * X12 + X12 * X22;
    float cc = X21 * X11 + X22 * X21;
    float dd = X21 * X12 + X22 * X22;
    X11 = a; X12 = bb; X21 = cc; X22 = dd;
  }
  float z = 0.f, y = 0.f;
#pragma unroll 8
  for (int k = 0; k < NC; ++k) {
    size_t o = (((size_t)b * NC + k) * PC + t) * 2;
    carryIn[o] = z; carryIn[o + 1] = y;
    float sz = carries[o], sy = carries[o + 1];
    float zn = X11 * z + X12 * y + sz;
    float yn = X21 * z + X22 * y + sy;
    z = zn; y = yn;
  }
  const int c = t & 1, p = t >> 1;
  if (mode == 1) {
    if (c == 0) {
      outp[OUT_BASE + (size_t)b * 256 + p] = z;
      outp[OUT_BASE + 1024 + (size_t)b * 256 + p] = y;
    }
  } else if (mode == 2) {
    outp[OUT_BASE + (size_t)c * 1024 + (size_t)b * 256 + p] = z;
    outp[OUT_BASE + 2048 + (size_t)c * 1024 + (size_t)b * 256 + p] = y;
  } else {
    outp[OUT_BASE + (size_t)b * PC + t] = z;
    outp[OUT_BASE + 2048 + (size_t)b * PC + t] = y;
  }
}

__global__ __launch_bounds__(512) void emit_gemm_kernel(const float* __restrict__ A_diag,
                                                        const float* __restrict__ step,
                                                        const float* __restrict__ carryIn,
                                                        const float* __restrict__ sBu,
                                                        const short* __restrict__ CtH,
                                                        const short* __restrict__ CtL,
                                                        float* __restrict__ outp) {
  __shared__ short ys_h[32][512];
  __shared__ short ys_l[32][512];
  const int t = threadIdx.x;
  const int b = blockIdx.y, ch = blockIdx.x;
  {
    float M11, M12, M21, M22;
    make_M(A_diag, step, t >> 1, M11, M12, M21, M22);
    size_t o = (((size_t)b * NC + ch) * PC + t) * 2;
    float z = carryIn[o], y = carryIn[o + 1];
    const float* fp = sBu + ((size_t)b * L_SEQ + (size_t)ch * CL) * PC + t;
#pragma unroll 8
    for (int i = 0; i < CL; ++i) {
      float f = fp[(size_t)i * PC];
      float zf = z + f;
      z = fmaf(M11, zf, M12 * y);
      y = fmaf(M21, zf, M22 * y);
      short hh, ll; f2hl(y, hh, ll);
      const int c = t ^ ((i & 7) << 3);
      ys_h[i][c] = hh;
      ys_l[i][c] = ll;
    }
  }
  __syncthreads();
  const int w = t >> 6, lane = t & 63;
  const int mt = w & 1;
  const int ntb = (w >> 1) * 2;
  const int lr = lane & 15, kb8 = (lane >> 4) * 8;
  const int mrow = mt * 16 + lr;
  const int msw = (mrow & 7) << 3;
  f32x4 acc[2] = {};
  for (int ks = 0; ks < 16; ++ks) {
    const int kc = (ks * 32 + kb8) ^ msw;
    s8v ah = *(const s8v*)&ys_h[mrow][kc];
    s8v al = *(const s8v*)&ys_l[mrow][kc];
#pragma unroll
    for (int q = 0; q < 2; ++q) {
      size_t fo = (((size_t)(ntb + q) * 16 + ks) * 64 + lane) * 8;
      s8v bh = *(const s8v*)&CtH[fo];
      s8v bl = *(const s8v*)&CtL[fo];
      acc[q] = __builtin_amdgcn_mfma_f32_16x16x32_bf16(ah, bh, acc[q], 0, 0, 0);
      acc[q] = __builtin_amdgcn_mfma_f32_16x16x32_bf16(al, bh, acc[q], 0, 0, 0);
      acc[q] = __builtin_amdgcn_mfma_f32_16x16x32_bf16(ah, bl, acc[q], 0, 0, 0);
    }
  }
  const int rb = (lane >> 4) * 4;
  const size_t rowbase = (size_t)b * L_SEQ + (size_t)ch * CL;
#pragma unroll
  for (int q = 0; q < 2; ++q) {
    const int col = (ntb + q) * 16 + lr;
#pragma unroll
    for (int r = 0; r < 4; ++r)
      outp[(rowbase + mt * 16 + rb + r) * H_DIM + col] = acc[q][r];
  }
}

// ---------------------------------------------------------------------------
extern "C" void kernel_launch(void* const* d_in, const int* in_sizes, int n_in,
                              void* d_out, int out_size, void* d_ws, size_t ws_size,
                              hipStream_t stream) {
  const float* A_diag = (const float*)d_in[0];
  const float* Bin    = (const float*)d_in[1];
  const float* Cin    = (const float*)d_in[2];
  const float* U      = (const float*)d_in[3];   // [B,L,H]
  const float* step   = (const float*)d_in[4];
  float* outp = (float*)d_out;
  float* ws = (float*)d_ws;

  int mode;
  if (out_size == OUT_BASE + 2048) mode = 1;        // real-only planar
  else if (out_size == OUT_BASE + 4096) mode = 2;   // planar re/im  (PASSED r7)
  else mode = 0;                                    // interleaved

  float* Bw      = ws;                            // 65536 f32
  short* CtH     = (short*)(ws + 65536);          // 65536 shorts
  short* CtL     = CtH + 65536;                   // 65536 shorts
  short* BwH     = (short*)(ws + 131072);         // 65536 shorts
  short* BwL     = BwH + 65536;                   // 65536 shorts
  float* carries = ws + 196608;                   // 524288 f32
  float* carryIn = ws + 720896;                   // 524288 f32
  float* sBu     = ws + 1245184;                  // 8388608 f32 (fallback only)

  prep_kernel<<<256, 256, 0, stream>>>(Bin, Cin, step, Bw, CtH, CtL, BwH, BwL);

  // Attempt cooperative launch directly; HIP validates co-residency and
  // launches nothing on error -> deterministic fallback decision per call.
  void* args[] = {(void*)&A_diag, (void*)&step, (void*)&U,
                  (void*)&BwH, (void*)&BwL, (void*)&CtH, (void*)&CtL,
                  (void*)&carries, (void*)&carryIn, (void*)&outp, (void*)&mode};
  hipError_t e = hipLaunchCooperativeKernel((void*)mega_kernel,
                                            dim3(NC, B_SZ), dim3(512),
                                            args, 0, stream);
  if (e != hipSuccess) {
    gemm_nt_mfma<128, 512><<<dim3(4, 256), 256, 0, stream>>>(U, Bw, sBu);
    scan_local_kernel<<<dim3(NC, B_SZ), 512, 0, stream>>>(A_diag, step, sBu, carries);
    combine_kernel<<<B_SZ, 512, 0, stream>>>(A_diag, step, carries, carryIn, outp, mode);
    emit_gemm_kernel<<<dim3(NC, B_SZ), 512, 0, stream>>>(A_diag, step, carryIn, sBu,
                                                         CtH, CtL, outp);
  }
}

// Round 12
// 123.182 us; speedup vs baseline: 1.9054x; 1.9054x over previous
//
#include <hip/hip_runtime.h>
#include <cstddef>

// LinOSS-IM: P=256, H=128, B=4, L=4096
#define P_DIM 256
#define H_DIM 128
#define B_SZ 4
#define L_SEQ 4096
#define PC 512                      // 2*P real components (re,im interleaved)
#define CL 32                       // scan chunk length
#define CLOG 5                      // log2(CL)
#define NC (L_SEQ / CL)             // 128 chunks
#define OUT_BASE (B_SZ * L_SEQ * H_DIM)

typedef __attribute__((ext_vector_type(8))) short s8v;   // 8 bf16 (4 VGPRs)
typedef __attribute__((ext_vector_type(4))) float f32x4; // MFMA accumulator

// ---- bf16 helpers (manual RNE) --------------------------------------------
__device__ __forceinline__ unsigned short f2bf(float x) {
  unsigned u = __builtin_bit_cast(unsigned, x);
  unsigned r = (u + 0x7FFFu + ((u >> 16) & 1u)) >> 16;
  return (unsigned short)r;
}
__device__ __forceinline__ float bf2f(unsigned short h) {
  return __builtin_bit_cast(float, (unsigned)h << 16);
}
__device__ __forceinline__ void f2hl(float x, short& h, short& l) {
  unsigned short hb = f2bf(x);
  float hf = bf2f(hb);
  unsigned short lb = f2bf(x - hf);
  h = (short)hb; l = (short)lb;
}

// M is REAL => complex recurrence splits into independent re/im chains.
__device__ __forceinline__ void make_M(const float* A_diag, const float* step, int p,
                                       float& M11, float& M12, float& M21, float& M22) {
  float Ad = A_diag[p], s = step[p];
  float sig = 1.0f / fmaf(s * s, Ad, 1.0f);   // schur
  M11 = 1.0f - s * s * Ad * sig;
  M12 = -s * Ad * sig;
  M21 = s * sig;
  M22 = sig;
}

// ---------------------------------------------------------------------------
// K0: prep fragment tables (512 KB total, L2/LLC-hot afterwards).
//  CtH/CtL: B-frags of Ct[k=(p,c)][h], idx=((nt*16+ks)*64+lane)*8+j,
//           n=nt*16+(lane&15), k=ks*32+(lane>>4)*8+j   (K=512 -> 16 ks)
//  BwH/BwL: B-frags of Bw[n=comp][k=h] = step*B, idx=((nt*4+ks)*64+lane)*8+j
// ---------------------------------------------------------------------------
__global__ __launch_bounds__(256) void prep_kernel(const float* __restrict__ Bin,
                                                   const float* __restrict__ Cin,
                                                   const float* __restrict__ step,
                                                   short* __restrict__ CtH,
                                                   short* __restrict__ CtL,
                                                   short* __restrict__ BwH,
                                                   short* __restrict__ BwL) {
  int idx = blockIdx.x * 256 + threadIdx.x;    // 0..65535
  {
    int j = idx & 7, lane = (idx >> 3) & 63, ks = (idx >> 9) & 15, nt = idx >> 13;
    int h = nt * 16 + (lane & 15);
    int k = ks * 32 + (lane >> 4) * 8 + j;
    float v = Cin[(size_t)h * PC + k] * ((k & 1) ? -1.0f : 1.0f);
    short hh, ll; f2hl(v, hh, ll);
    CtH[idx] = hh; CtL[idx] = ll;
  }
  {
    int j = idx & 7, lane = (idx >> 3) & 63, ks = (idx >> 9) & 3, nt = idx >> 11;
    int n = nt * 16 + (lane & 15);              // comp
    int k = ks * 32 + (lane >> 4) * 8 + j;      // h
    int p = n >> 1, c = n & 1;
    float v = step[p] * Bin[(p * H_DIM + k) * 2 + c];
    short hh, ll; f2hl(v, hh, ll);
    BwH[idx] = hh; BwL[idx] = ll;
  }
}

// ---------------------------------------------------------------------------
// Shared device routine [HW-validated r9 mega A0-A2]: build Bu tile
// [32 t][512 comp] for (b, ch) into Fs (XOR-swizzled col ^= (row&7)<<3) via
// split-bf16 MFMA against L2-hot Bw fragments. Output is bitwise-deterministic
// (MFMA/convert DAG fixes values independent of scheduling), so front and
// emit reconstruct identical tiles.
// ---------------------------------------------------------------------------
__device__ __forceinline__ void build_bu_tile(float (*Fs)[512],
                                              const float* __restrict__ U,
                                              const short* __restrict__ BwH,
                                              const short* __restrict__ BwL,
                                              int b, int ch, int t) {
  const int lane = t & 63, w = t >> 6;
  const int lr = lane & 15, kb8 = (lane >> 4) * 8, rb = (lane >> 4) * 4;

  // A0: stage U tile [32][128] as split-bf16 (aliased into Fs)
  short* Ush = (short*)&Fs[0][0];              // [32][136]
  short* Usl = Ush + 32 * 136;                 // 17408 B total
  {
    const int row = t >> 4, c8 = (t & 15) * 8;
    const float* up = &U[((size_t)b * L_SEQ + (size_t)ch * CL + row) * H_DIM + c8];
    float4 u0 = *(const float4*)up, u1 = *(const float4*)(up + 4);
    s8v h8, l8; short hh, ll;
    f2hl(u0.x, hh, ll); h8[0] = hh; l8[0] = ll;
    f2hl(u0.y, hh, ll); h8[1] = hh; l8[1] = ll;
    f2hl(u0.z, hh, ll); h8[2] = hh; l8[2] = ll;
    f2hl(u0.w, hh, ll); h8[3] = hh; l8[3] = ll;
    f2hl(u1.x, hh, ll); h8[4] = hh; l8[4] = ll;
    f2hl(u1.y, hh, ll); h8[5] = hh; l8[5] = ll;
    f2hl(u1.z, hh, ll); h8[6] = hh; l8[6] = ll;
    f2hl(u1.w, hh, ll); h8[7] = hh; l8[7] = ll;
    *(s8v*)&Ush[row * 136 + c8] = h8;
    *(s8v*)&Usl[row * 136 + c8] = l8;
  }
  __syncthreads();

  // A1: Bu GEMM. wave w: mt=w&1, n-tiles ntbA..ntbA+7
  const int mt = w & 1;
  const int ntbA = (w >> 1) * 8;
  f32x4 accA[8] = {};
#pragma unroll
  for (int ks = 0; ks < 4; ++ks) {
    s8v ah = *(const s8v*)&Ush[(mt * 16 + lr) * 136 + ks * 32 + kb8];
    s8v al = *(const s8v*)&Usl[(mt * 16 + lr) * 136 + ks * 32 + kb8];
#pragma unroll
    for (int q = 0; q < 8; ++q) {
      size_t fo = (((size_t)(ntbA + q) * 4 + ks) * 64 + lane) * 8;
      s8v bh = *(const s8v*)&BwH[fo];
      s8v bl = *(const s8v*)&BwL[fo];
      accA[q] = __builtin_amdgcn_mfma_f32_16x16x32_bf16(ah, bh, accA[q], 0, 0, 0);
      accA[q] = __builtin_amdgcn_mfma_f32_16x16x32_bf16(al, bh, accA[q], 0, 0, 0);
      accA[q] = __builtin_amdgcn_mfma_f32_16x16x32_bf16(ah, bl, accA[q], 0, 0, 0);
    }
  }
  __syncthreads();                             // U-stage reads done

  // A2: scatter acc -> Fs[time][comp], swizzled
#pragma unroll
  for (int q = 0; q < 8; ++q)
#pragma unroll
    for (int r = 0; r < 4; ++r) {
      int row = mt * 16 + rb + r;
      int col = (ntbA + q) * 16 + lr;
      Fs[row][col ^ ((row & 7) << 3)] = accA[q][r];
    }
  __syncthreads();
}

// ---------------------------------------------------------------------------
// K1 (front): per (ch, b): Bu tile -> LDS, local 32-step scan (zero init),
// write chunk-final (z,y) to carries. [r9-validated phases; r7-validated
// cross-kernel carries handoff pattern.]
// ---------------------------------------------------------------------------
__global__ __launch_bounds__(512, 4) void front_kernel(const float* __restrict__ A_diag,
                                                       const float* __restrict__ step,
                                                       const float* __restrict__ U,
                                                       const short* __restrict__ BwH,
                                                       const short* __restrict__ BwL,
                                                       float* __restrict__ carries) {
  __shared__ float Fs[32][512];                // 64KB
  const int t = threadIdx.x;
  const int ch = blockIdx.x, b = blockIdx.y;

  build_bu_tile(Fs, U, BwH, BwL, b, ch, t);

  float M11, M12, M21, M22;
  make_M(A_diag, step, t >> 1, M11, M12, M21, M22);    // t = comp
  float z = 0.f, y = 0.f;
#pragma unroll 8
  for (int i = 0; i < CL; ++i) {
    float f = Fs[i][t ^ ((i & 7) << 3)];
    float zf = z + f;
    z = fmaf(M11, zf, M12 * y);
    y = fmaf(M21, zf, M22 * y);
  }
  size_t o = (((size_t)b * NC + ch) * PC + t) * 2;
  carries[o] = z; carries[o + 1] = y;
}

// ---------------------------------------------------------------------------
// K2 (combine) — EXACT r7-validated kernel: 4 blocks, serial chain over NC
// chunk carries with Mc = M^CL; writes per-chunk carryIn and the z_f/y_f
// tail (mode logic validated r7/r9).
// ---------------------------------------------------------------------------
__global__ __launch_bounds__(512) void combine_kernel(const float* __restrict__ A_diag,
                                                      const float* __restrict__ step,
                                                      const float* __restrict__ carries,
                                                      float* __restrict__ carryIn,
                                                      float* __restrict__ outp,
                                                      int mode) {
  const int t = threadIdx.x;
  const int b = blockIdx.x;
  float M11, M12, M21, M22;
  make_M(A_diag, step, t >> 1, M11, M12, M21, M22);
  float X11 = M11, X12 = M12, X21 = M21, X22 = M22;
#pragma unroll
  for (int i = 0; i < CLOG; ++i) {             // Mc = M^CL
    float a = X11 * X11 + X12 * X21;
    float bb = X11 * X12 + X12 * X22;
    float cc = X21 * X11 + X22 * X21;
    float dd = X21 * X12 + X22 * X22;
    X11 = a; X12 = bb; X21 = cc; X22 = dd;
  }
  float z = 0.f, y = 0.f;
#pragma unroll 8
  for (int k = 0; k < NC; ++k) {
    size_t o = (((size_t)b * NC + k) * PC + t) * 2;
    carryIn[o] = z; carryIn[o + 1] = y;
    float sz = carries[o], sy = carries[o + 1];
    float zn = X11 * z + X12 * y + sz;
    float yn = X21 * z + X22 * y + sy;
    z = zn; y = yn;
  }
  const int c = t & 1, p = t >> 1;
  if (mode == 1) {
    if (c == 0) {                              // real-only planar [2][B][P]
      outp[OUT_BASE + (size_t)b * 256 + p] = z;
      outp[OUT_BASE + 1024 + (size_t)b * 256 + p] = y;
    }
  } else if (mode == 2) {                      // planar re/im planes
    outp[OUT_BASE + (size_t)c * 1024 + (size_t)b * 256 + p] = z;
    outp[OUT_BASE + 2048 + (size_t)c * 1024 + (size_t)b * 256 + p] = y;
  } else {                                     // interleaved complex view
    outp[OUT_BASE + (size_t)b * PC + t] = z;
    outp[OUT_BASE + 2048 + (size_t)b * PC + t] = y;
  }
}

// ---------------------------------------------------------------------------
// K3 (emit): per (ch, b): read seed carryIn[ch] (r7-validated handoff),
// rebuild Bu tile (bitwise-identical to front's), seeded scan + in-place
// bf16 hi|lo pack [r9-validated], out GEMM vs L2-hot Ct frags [r9-validated].
// ---------------------------------------------------------------------------
__global__ __launch_bounds__(512, 4) void emit_kernel(const float* __restrict__ A_diag,
                                                      const float* __restrict__ step,
                                                      const float* __restrict__ U,
                                                      const short* __restrict__ BwH,
                                                      const short* __restrict__ BwL,
                                                      const float* __restrict__ carryIn,
                                                      const short* __restrict__ CtH,
                                                      const short* __restrict__ CtL,
                                                      float* __restrict__ outp) {
  __shared__ float Fs[32][512];                // 64KB
  const int t = threadIdx.x;
  const int ch = blockIdx.x, b = blockIdx.y;
  const int lane = t & 63, w = t >> 6;
  const int lr = lane & 15, kb8 = (lane >> 4) * 8, rb = (lane >> 4) * 4;

  float M11, M12, M21, M22;
  make_M(A_diag, step, t >> 1, M11, M12, M21, M22);

  // seed from combine's carryIn
  size_t o = (((size_t)b * NC + ch) * PC + t) * 2;
  float z = carryIn[o], y = carryIn[o + 1];

  build_bu_tile(Fs, U, BwH, BwL, b, ch, t);

  // seeded scan; pack ys bf16 hi|lo u32 in place (same thread+addr: race-free)
#pragma unroll 8
  for (int i = 0; i < CL; ++i) {
    const int cswz = t ^ ((i & 7) << 3);
    float f = Fs[i][cswz];
    float zf = z + f;
    z = fmaf(M11, zf, M12 * y);
    y = fmaf(M21, zf, M22 * y);
    short hh, ll; f2hl(y, hh, ll);
    unsigned u = ((unsigned)(unsigned short)hh << 16) | (unsigned)(unsigned short)ll;
    Fs[i][cswz] = __builtin_bit_cast(float, u);
  }
  __syncthreads();

  // out GEMM [32 t][128 h] = ys[32][512] x Ct[512][128]
  const int mt = w & 1;
  const int ntbC = (w >> 1) * 2;
  const int mrow = mt * 16 + lr;
  const int msw = (mrow & 7) << 3;
  f32x4 accC[2] = {};
  for (int ks = 0; ks < 16; ++ks) {
    const unsigned* ap = (const unsigned*)&Fs[mrow][(ks * 32 + kb8) ^ msw];
    uint4 w0 = *(const uint4*)ap;
    uint4 w1 = *(const uint4*)(ap + 4);
    s8v ah, al;
    ah[0] = (short)(w0.x >> 16); al[0] = (short)(w0.x & 0xffff);
    ah[1] = (short)(w0.y >> 16); al[1] = (short)(w0.y & 0xffff);
    ah[2] = (short)(w0.z >> 16); al[2] = (short)(w0.z & 0xffff);
    ah[3] = (short)(w0.w >> 16); al[3] = (short)(w0.w & 0xffff);
    ah[4] = (short)(w1.x >> 16); al[4] = (short)(w1.x & 0xffff);
    ah[5] = (short)(w1.y >> 16); al[5] = (short)(w1.y & 0xffff);
    ah[6] = (short)(w1.z >> 16); al[6] = (short)(w1.z & 0xffff);
    ah[7] = (short)(w1.w >> 16); al[7] = (short)(w1.w & 0xffff);
#pragma unroll
    for (int q = 0; q < 2; ++q) {
      size_t fo = (((size_t)(ntbC + q) * 16 + ks) * 64 + lane) * 8;
      s8v bh = *(const s8v*)&CtH[fo];
      s8v bl = *(const s8v*)&CtL[fo];
      accC[q] = __builtin_amdgcn_mfma_f32_16x16x32_bf16(ah, bh, accC[q], 0, 0, 0);
      accC[q] = __builtin_amdgcn_mfma_f32_16x16x32_bf16(al, bh, accC[q], 0, 0, 0);
      accC[q] = __builtin_amdgcn_mfma_f32_16x16x32_bf16(ah, bl, accC[q], 0, 0, 0);
    }
  }
  const size_t rowbase = (size_t)b * L_SEQ + (size_t)ch * CL;
#pragma unroll
  for (int q = 0; q < 2; ++q) {
    const int col = (ntbC + q) * 16 + lr;
#pragma unroll
    for (int r = 0; r < 4; ++r)
      outp[(rowbase + mt * 16 + rb + r) * H_DIM + col] = accC[q][r];
  }
}

// ---------------------------------------------------------------------------
extern "C" void kernel_launch(void* const* d_in, const int* in_sizes, int n_in,
                              void* d_out, int out_size, void* d_ws, size_t ws_size,
                              hipStream_t stream) {
  const float* A_diag = (const float*)d_in[0];
  const float* Bin    = (const float*)d_in[1];
  const float* Cin    = (const float*)d_in[2];
  const float* U      = (const float*)d_in[3];   // [B,L,H]
  const float* step   = (const float*)d_in[4];
  float* outp = (float*)d_out;
  float* ws = (float*)d_ws;

  int mode;
  if (out_size == OUT_BASE + 2048) mode = 1;        // real-only planar
  else if (out_size == OUT_BASE + 4096) mode = 2;   // planar re/im
  else mode = 0;                                    // interleaved

  short* CtH     = (short*)ws;                    // 65536 shorts
  short* CtL     = CtH + 65536;                   // 65536 shorts
  short* BwH     = CtL + 65536;                   // 65536 shorts
  short* BwL     = BwH + 65536;                   // 65536 shorts
  float* carries = ws + 131072;                   // 524288 f32 (2 MB)
  float* carryIn = carries + 524288;              // 524288 f32 (2 MB)
  // total ws use: 4.5 MB

  prep_kernel<<<256, 256, 0, stream>>>(Bin, Cin, step, CtH, CtL, BwH, BwL);
  front_kernel<<<dim3(NC, B_SZ), 512, 0, stream>>>(A_diag, step, U, BwH, BwL, carries);
  combine_kernel<<<B_SZ, 512, 0, stream>>>(A_diag, step, carries, carryIn, outp, mode);
  emit_kernel<<<dim3(NC, B_SZ), 512, 0, stream>>>(A_diag, step, U, BwH, BwL, carryIn,
                                                  CtH, CtL, outp);
}